// Round 1
// baseline (45461.435 us; speedup 1.0000x reference)
//
#include <hip/hip_runtime.h>

#define B_ 64
#define T_ 512
#define D_ 1024
#define H_ 1024
#define NG_ 4096   // 4*H

// xT[t][d][b] = x[b][t][d]   (33,554,432 elements)
__global__ __launch_bounds__(256) void k_trans_x(const float* __restrict__ x,
                                                 float* __restrict__ xT) {
  int idx = blockIdx.x * 256 + threadIdx.x;
  int b = idx & 63;
  int d = (idx >> 6) & (D_ - 1);
  int t = idx >> 16;
  xT[idx] = x[b * (T_ * D_) + t * D_ + d];
}

// hT[k][b] = h[b][k]
__global__ __launch_bounds__(256) void k_trans_h_fwd(const float* __restrict__ h,
                                                     float* __restrict__ hT) {
  int idx = blockIdx.x * 256 + threadIdx.x;  // idx = k*64 + b
  int b = idx & 63;
  int k = idx >> 6;
  hT[idx] = h[b * H_ + k];
}

// h[b][k] = hT[k][b]
__global__ __launch_bounds__(256) void k_trans_h_back(const float* __restrict__ hT,
                                                      float* __restrict__ h) {
  int idx = blockIdx.x * 256 + threadIdx.x;  // idx = b*1024 + k
  int k = idx & (H_ - 1);
  int b = idx >> 10;
  h[idx] = hT[k * 64 + b];
}

// One LSTM time step.
// Grid: 256 blocks (4 h-columns each) x 512 threads (8 waves, k-split 8).
// gates[b][n] = bias[n] + sum_k hT_in[k][b]*Wh[k][n] + sum_d xT_t[d][b]*Wi[d][n]
// XFAST=true: x pre-transposed in ws. XFAST=false: read x directly (slow fallback).
template <bool XFAST>
__global__ __launch_bounds__(512) void k_lstm_step(
    const float* __restrict__ xsrc,   // XFAST ? xT + t*65536 : x + t*D_
    const float* __restrict__ Wi,     // [1024][4096]
    const float* __restrict__ Wh,     // [1024][4096]
    const float* __restrict__ bias,   // [4096]
    const float* __restrict__ hT_in,  // [1024][64]
    float* __restrict__ hT_out,       // [1024][64]
    float* __restrict__ c_state,      // [64][1024] in-place
    float* __restrict__ ys_t)         // d_out + 2*65536 + t*H_
{
  __shared__ float red[8][64][17];
  const int tid = threadIdx.x;
  const int lane = tid & 63;
  const int w = tid >> 6;              // 0..7, k-split index
  const int hbase = blockIdx.x * 4;

  float acc[4][4];                     // [c 0..3][gate 0..3]
#pragma unroll
  for (int c = 0; c < 4; ++c)
#pragma unroll
    for (int g = 0; g < 4; ++g) acc[c][g] = 0.f;

  const int k0 = w * 128;
#pragma unroll 2
  for (int k = k0; k < k0 + 128; ++k) {
    float hv = hT_in[k * 64 + lane];
    float xv;
    if (XFAST) {
      xv = xsrc[k * 64 + lane];                       // xT[t][k][b]
    } else {
      xv = xsrc[lane * (T_ * D_) + k];                // x[b][t][k]
    }
#pragma unroll
    for (int g = 0; g < 4; ++g) {
      const float4 wh = *(const float4*)(Wh + k * NG_ + g * H_ + hbase);
      const float4 wi = *(const float4*)(Wi + k * NG_ + g * H_ + hbase);
      acc[0][g] = fmaf(hv, wh.x, acc[0][g]);
      acc[1][g] = fmaf(hv, wh.y, acc[1][g]);
      acc[2][g] = fmaf(hv, wh.z, acc[2][g]);
      acc[3][g] = fmaf(hv, wh.w, acc[3][g]);
      acc[0][g] = fmaf(xv, wi.x, acc[0][g]);
      acc[1][g] = fmaf(xv, wi.y, acc[1][g]);
      acc[2][g] = fmaf(xv, wi.z, acc[2][g]);
      acc[3][g] = fmaf(xv, wi.w, acc[3][g]);
    }
  }

  // cross-wave reduction of the 8 k-split partials
#pragma unroll
  for (int c = 0; c < 4; ++c)
#pragma unroll
    for (int g = 0; g < 4; ++g) red[w][lane][c * 4 + g] = acc[c][g];
  __syncthreads();

  if (tid < 256) {
    const int b = tid >> 2;
    const int c = tid & 3;
    const int h = hbase + c;
    float v[4];
#pragma unroll
    for (int g = 0; g < 4; ++g) {
      float s = bias[g * H_ + h];
#pragma unroll
      for (int ww = 0; ww < 8; ++ww) s += red[ww][b][c * 4 + g];
      v[g] = s;
    }
    const float cold = c_state[b * H_ + h];
    const float si = 1.f / (1.f + expf(-v[0]));
    const float sf = 1.f / (1.f + expf(-v[1]));
    const float gt = tanhf(v[2]);
    const float so = 1.f / (1.f + expf(-v[3]));
    const float cn = sf * cold + si * gt;
    const float hn = so * tanhf(cn);
    c_state[b * H_ + h] = cn;
    hT_out[h * 64 + b] = hn;
    ys_t[b * (T_ * H_) + h] = hn;
  }
}

extern "C" void kernel_launch(void* const* d_in, const int* in_sizes, int n_in,
                              void* d_out, int out_size, void* d_ws, size_t ws_size,
                              hipStream_t stream) {
  const float* c0   = (const float*)d_in[0];
  const float* h0   = (const float*)d_in[1];
  const float* x    = (const float*)d_in[2];
  const float* Wi   = (const float*)d_in[3];
  const float* Wh   = (const float*)d_in[4];
  const float* bias = (const float*)d_in[5];

  float* out     = (float*)d_out;
  float* c_state = out;                 // [64][1024] final c
  float* h_final = out + B_ * H_;       // [64][1024] final h
  float* ys      = out + 2 * B_ * H_;   // [64][512][1024]

  const size_t xT_elems = (size_t)T_ * D_ * B_;          // 33,554,432
  const size_t need_fast = (xT_elems + 2 * B_ * H_) * sizeof(float);
  const bool xfast = ws_size >= need_fast;

  float* xT = (float*)d_ws;
  float* hA;
  float* hB;
  if (xfast) {
    hA = xT + xT_elems;
  } else {
    hA = (float*)d_ws;                  // only need the two h buffers
  }
  hB = hA + B_ * H_;

  // init state: c <- c0 (in d_out, updated in place), hA <- h0^T
  hipMemcpyAsync(c_state, c0, B_ * H_ * sizeof(float), hipMemcpyDeviceToDevice, stream);
  k_trans_h_fwd<<<B_ * H_ / 256, 256, 0, stream>>>(h0, hA);
  if (xfast) {
    k_trans_x<<<(int)(xT_elems / 256), 256, 0, stream>>>(x, xT);
  }

  for (int t = 0; t < T_; ++t) {
    const float* hin = (t & 1) ? hB : hA;
    float* hout      = (t & 1) ? hA : hB;
    float* ys_t = ys + (size_t)t * H_;
    if (xfast) {
      k_lstm_step<true><<<256, 512, 0, stream>>>(
          xT + (size_t)t * (D_ * B_), Wi, Wh, bias, hin, hout, c_state, ys_t);
    } else {
      k_lstm_step<false><<<256, 512, 0, stream>>>(
          x + (size_t)t * D_, Wi, Wh, bias, hin, hout, c_state, ys_t);
    }
  }
  // T_ even -> last write went to hA
  k_trans_h_back<<<B_ * H_ / 256, 256, 0, stream>>>(hA, h_final);
}